// Round 5
// baseline (582.663 us; speedup 1.0000x reference)
//
#include <hip/hip_runtime.h>
#include <stdint.h>

#define D 128
#define MT 64
#define XS 392          // X row stride in shorts (49*16B rows -> conflict-free, measured)
#define HS 136          // H row stride in shorts (17*16B)

typedef short short8 __attribute__((ext_vector_type(8)));
typedef float f32x16 __attribute__((ext_vector_type(16)));

__device__ __forceinline__ unsigned short f2bf(float f) {
    union { float f; uint32_t u; } v;
    v.f = f;
    uint32_t u = v.u;
    uint32_t r = (u + 0x7fffu + ((u >> 16) & 1u)) >> 16;  // RNE
    return (unsigned short)r;
}

// Pack W1 (384x128) / W2 (128x128) fp32 row-major -> bf16 MFMA-B fragment order:
// frag index ((kt*4 + nt)*64 + lane)*8 + j holds W[k = kt*16 + (lane>>5)*8 + j][n = nt*32 + (lane&31)]
__global__ void pack_weights_kernel(const float* __restrict__ W1,
                                    const float* __restrict__ W2,
                                    unsigned short* __restrict__ W1p,
                                    unsigned short* __restrict__ W2p) {
    int t = blockIdx.x * 256 + threadIdx.x;
    if (t < 6144) {               // W1: 24 ksteps * 4 colblocks * 64 lanes
        int kt = t >> 8, nt = (t >> 6) & 3, lane = t & 63;
        int n = nt * 32 + (lane & 31);
        int kb = kt * 16 + (lane >> 5) * 8;
        unsigned short* dst = W1p + t * 8;
        #pragma unroll
        for (int j = 0; j < 8; ++j) dst[j] = f2bf(W1[(kb + j) * D + n]);
    } else if (t < 8192) {        // W2: 8 ksteps * 4 colblocks * 64 lanes
        int u = t - 6144;
        int kt = u >> 8, nt = (u >> 6) & 3, lane = u & 63;
        int n = nt * 32 + (lane & 31);
        int kb = kt * 16 + (lane >> 5) * 8;
        unsigned short* dst = W2p + u * 8;
        #pragma unroll
        for (int j = 0; j < 8; ++j) dst[j] = f2bf(W2[(kb + j) * D + n]);
    }
}

// Persistent single-buffer pipeline: grid = min(nblk,512), 512 threads = 8 waves,
// one 32x32 output tile per wave. LDS = X(50176B) + H(17408B, NOT aliased) = 67584B
// -> 2 blocks/CU = 16 waves/CU; launch_bounds(512,4) -> 128 VGPR budget.
// Per tile: STAGE(payload gathered LAST iter) ; barrier ; issue GATHER(tile+1) and
// eidx(tile+2) ; GEMM1 ; Hwrite ; barrier ; GEMM2 ; store. The gather payload flies
// ~the whole tile (GEMM1+GEMM2+store+stage) before STAGE consumes it; X is safe to
// rewrite after the H-barrier because GEMM2 reads only H.
__global__ __launch_bounds__(512, 4) void edge_mlp_kernel(
    const float* __restrict__ x_node,
    const float* __restrict__ x_edge,
    const int* __restrict__ eidx,
    const unsigned short* __restrict__ W1p,
    const unsigned short* __restrict__ W2p,
    const float* __restrict__ b1,
    const float* __restrict__ b2,
    float* __restrict__ out,
    int E, int nblk) {
    __shared__ unsigned short Xs[MT * XS];   // 50176 B
    __shared__ unsigned short Hs[MT * HS];   // 17408 B

    const int t = threadIdx.x;
    const int g = gridDim.x;
    const int bid = blockIdx.x;

    const int lane32 = t & 31;
    const int rsub = t >> 5;              // 0..15
    const int w = t >> 6;                 // wave 0..7
    const int cb = w & 3;                 // column block
    const int rt = w >> 2;                // row tile
    const int lane = t & 63;
    const int lrow = lane & 31;
    const int khalf = (lane >> 5) * 8;
    const int n = cb * 32 + lrow;
    const int rbump = (lane >> 5) * 4;
    const int arow = rt * 32 + lrow;

    const unsigned short* bp1 = W1p + ((size_t)cb * 64 + lane) * 8;
    const unsigned short* bp2 = W2p + ((size_t)cb * 64 + lane) * 8;
    const float b1v = b1[n];
    const float b2v = b2[n];

    int2 e[4];
    int rg[4];
    float4 v0[4], v1[4], v2[4];

    // ---- prologue: eidx(bid) -> gather(bid) in flight; eidx(bid+g) in flight ----
    {
        int tb = bid * MT;
        #pragma unroll
        for (int rb = 0; rb < 4; ++rb) {
            int r = tb + rb * 16 + rsub;
            rg[rb] = r < E ? r : E - 1;
            e[rb] = ((const int2*)eidx)[rg[rb]];
        }
        #pragma unroll
        for (int rb = 0; rb < 4; ++rb) {
            v0[rb] = ((const float4*)(x_node + (size_t)e[rb].x * D))[lane32];
            v1[rb] = ((const float4*)(x_node + (size_t)e[rb].y * D))[lane32];
            v2[rb] = ((const float4*)(x_edge + (size_t)rg[rb] * D))[lane32];
        }
        int nt2 = bid + g < nblk ? bid + g : nblk - 1;
        int tb2 = nt2 * MT;
        #pragma unroll
        for (int rb = 0; rb < 4; ++rb) {
            int r = tb2 + rb * 16 + rsub;
            rg[rb] = r < E ? r : E - 1;
            e[rb] = ((const int2*)eidx)[rg[rb]];
        }
    }

    for (int tile = bid; tile < nblk; tile += g) {
        // ---- STAGE: payload (gathered last iter / prologue) -> LDS ----
        #pragma unroll
        for (int rb = 0; rb < 4; ++rb) {
            unsigned short* base = &Xs[(rb * 16 + rsub) * XS + lane32 * 4];
            ushort4 p;
            p.x = f2bf(v0[rb].x); p.y = f2bf(v0[rb].y);
            p.z = f2bf(v0[rb].z); p.w = f2bf(v0[rb].w);
            *(ushort4*)(base) = p;
            p.x = f2bf(v1[rb].x); p.y = f2bf(v1[rb].y);
            p.z = f2bf(v1[rb].z); p.w = f2bf(v1[rb].w);
            *(ushort4*)(base + 128) = p;
            p.x = f2bf(v2[rb].x); p.y = f2bf(v2[rb].y);
            p.z = f2bf(v2[rb].z); p.w = f2bf(v2[rb].w);
            *(ushort4*)(base + 256) = p;
        }
        __syncthreads();   // X visible (also: prev GEMM2 H-reads done before next H write)

        // ---- issue next tile's gathers (eidx already arrived) + eidx two ahead ----
        #pragma unroll
        for (int rb = 0; rb < 4; ++rb) {
            v0[rb] = ((const float4*)(x_node + (size_t)e[rb].x * D))[lane32];
            v1[rb] = ((const float4*)(x_node + (size_t)e[rb].y * D))[lane32];
            v2[rb] = ((const float4*)(x_edge + (size_t)rg[rb] * D))[lane32];
        }
        {
            int nt2 = tile + 2 * g < nblk ? tile + 2 * g : nblk - 1;
            int tb2 = nt2 * MT;
            #pragma unroll
            for (int rb = 0; rb < 4; ++rb) {
                int r = tb2 + rb * 16 + rsub;
                rg[rb] = r < E ? r : E - 1;
                e[rb] = ((const int2*)eidx)[rg[rb]];
            }
        }

        // ---- GEMM1: H = relu(X_cat @ W1 + b1), K = 384 ----
        f32x16 acc;
        #pragma unroll
        for (int i = 0; i < 16; ++i) acc[i] = 0.f;
        #pragma unroll 8
        for (int kt = 0; kt < 24; ++kt) {
            short8 a = *(const short8*)&Xs[arow * XS + kt * 16 + khalf];
            short8 b = *(const short8*)(bp1 + (size_t)kt * 2048);
            acc = __builtin_amdgcn_mfma_f32_32x32x16_bf16(a, b, acc, 0, 0, 0);
        }
        #pragma unroll
        for (int r = 0; r < 16; ++r) {
            int rr = rt * 32 + (r & 3) + 8 * (r >> 2) + rbump;
            Hs[rr * HS + n] = f2bf(fmaxf(acc[r] + b1v, 0.f));
        }
        __syncthreads();   // H visible

        // ---- GEMM2: OUT = H @ W2 + b2, K = 128 ----
        f32x16 c;
        #pragma unroll
        for (int i = 0; i < 16; ++i) c[i] = 0.f;
        #pragma unroll
        for (int kt = 0; kt < 8; ++kt) {
            short8 a = *(const short8*)&Hs[arow * HS + kt * 16 + khalf];
            short8 wb = *(const short8*)(bp2 + (size_t)kt * 2048);
            c = __builtin_amdgcn_mfma_f32_32x32x16_bf16(a, wb, c, 0, 0, 0);
        }
        {
            const int r0 = tile * MT;
            #pragma unroll
            for (int r = 0; r < 16; ++r) {
                int rr = rt * 32 + (r & 3) + 8 * (r >> 2) + rbump;
                int rgl = r0 + rr;
                if (rgl < E) out[(size_t)rgl * D + n] = c[r] + b2v;
            }
        }
    }
}

extern "C" void kernel_launch(void* const* d_in, const int* in_sizes, int n_in,
                              void* d_out, int out_size, void* d_ws, size_t ws_size,
                              hipStream_t stream) {
    const float* x_node = (const float*)d_in[0];
    const float* x_edge = (const float*)d_in[1];
    const int*   eidx   = (const int*)d_in[2];
    const float* W1     = (const float*)d_in[3];
    const float* b1     = (const float*)d_in[4];
    const float* W2     = (const float*)d_in[5];
    const float* b2     = (const float*)d_in[6];
    float* out = (float*)d_out;

    const int E = in_sizes[1] / D;

    unsigned short* W1p = (unsigned short*)d_ws;          // 6144*8 bf16 = 96 KB
    unsigned short* W2p = W1p + 6144 * 8;                 // 2048*8 bf16 = 32 KB

    pack_weights_kernel<<<32, 256, 0, stream>>>(W1, W2, W1p, W2p);

    int nblk = (E + MT - 1) / MT;
    int grid = nblk < 512 ? nblk : 512;
    if (grid < 1) grid = 1;
    edge_mlp_kernel<<<grid, 512, 0, stream>>>(x_node, x_edge, eidx, W1p, W2p, b1, b2, out, E, nblk);
}

// Round 6
// 521.410 us; speedup vs baseline: 1.1175x; 1.1175x over previous
//
#include <hip/hip_runtime.h>
#include <stdint.h>

#define D 128
#define MT 32
#define XS 392          // X row stride in shorts (49*16B rows -> conflict-free, measured)
#define HS 136          // H row stride in shorts (17*16B)

typedef short short8 __attribute__((ext_vector_type(8)));
typedef float f32x16 __attribute__((ext_vector_type(16)));

__device__ __forceinline__ unsigned short f2bf(float f) {
    union { float f; uint32_t u; } v;
    v.f = f;
    uint32_t u = v.u;
    uint32_t r = (u + 0x7fffu + ((u >> 16) & 1u)) >> 16;  // RNE
    return (unsigned short)r;
}

// Pack W1 (384x128) / W2 (128x128) fp32 row-major -> bf16 MFMA-B fragment order:
// frag index ((kt*4 + nt)*64 + lane)*8 + j holds W[k = kt*16 + (lane>>5)*8 + j][n = nt*32 + (lane&31)]
__global__ void pack_weights_kernel(const float* __restrict__ W1,
                                    const float* __restrict__ W2,
                                    unsigned short* __restrict__ W1p,
                                    unsigned short* __restrict__ W2p) {
    int t = blockIdx.x * 256 + threadIdx.x;
    if (t < 6144) {               // W1: 24 ksteps * 4 colblocks * 64 lanes
        int kt = t >> 8, nt = (t >> 6) & 3, lane = t & 63;
        int n = nt * 32 + (lane & 31);
        int kb = kt * 16 + (lane >> 5) * 8;
        unsigned short* dst = W1p + t * 8;
        #pragma unroll
        for (int j = 0; j < 8; ++j) dst[j] = f2bf(W1[(kb + j) * D + n]);
    } else if (t < 8192) {        // W2: 8 ksteps * 4 colblocks * 64 lanes
        int u = t - 6144;
        int kt = u >> 8, nt = (u >> 6) & 3, lane = u & 63;
        int n = nt * 32 + (lane & 31);
        int kb = kt * 16 + (lane >> 5) * 8;
        unsigned short* dst = W2p + u * 8;
        #pragma unroll
        for (int j = 0; j < 8; ++j) dst[j] = f2bf(W2[(kb + j) * D + n]);
    }
}

// 32 edges per block, 256 threads = 4 waves; wave w owns output columns [32w, 32w+32)
// of the single 32-row tile. Little's-law fix: 6 blocks/CU (LDS 25088B) = 6 concurrent
// eidx->gather dependency chains per CU (vs 3 at MT=64), the quantity all prior rounds
// left invariant. x_edge gathers (linear addr) issue BEFORE the eidx round-trip.
// H aliases X (barrier-separated). Same stage/fragment layout as the proven MT=64 kernel.
__global__ __launch_bounds__(256, 6) void edge_mlp_kernel(
    const float* __restrict__ x_node,
    const float* __restrict__ x_edge,
    const int* __restrict__ eidx,
    const unsigned short* __restrict__ W1p,
    const unsigned short* __restrict__ W2p,
    const float* __restrict__ b1,
    const float* __restrict__ b2,
    float* __restrict__ out,
    int E) {
    __shared__ unsigned short lds[MT * XS];    // 25088 B
    unsigned short* Hs = lds;                  // aliased, stride 136 (17*16B)

    const int t = threadIdx.x;
    const int r0 = blockIdx.x * MT;

    // ---- stage: x_edge first (no idx dependency), then eidx -> v0/v1 gathers ----
    {
        const int lane32 = t & 31;
        const int rsub = t >> 5;               // 0..7

        int rgc[4];
        float4 v2[4];
        #pragma unroll
        for (int rb = 0; rb < 4; ++rb) {       // linear-index stream: issue immediately
            int rg = r0 + rb * 8 + rsub;
            rgc[rb] = rg < E ? rg : E - 1;
            v2[rb] = ((const float4*)(x_edge + (size_t)rgc[rb] * D))[lane32];
        }
        int2 e[4];
        #pragma unroll
        for (int rb = 0; rb < 4; ++rb)
            e[rb] = ((const int2*)eidx)[rgc[rb]];
        float4 v0[4], v1[4];
        #pragma unroll
        for (int rb = 0; rb < 4; ++rb) {
            v0[rb] = ((const float4*)(x_node + (size_t)e[rb].x * D))[lane32];
            v1[rb] = ((const float4*)(x_node + (size_t)e[rb].y * D))[lane32];
        }
        #pragma unroll
        for (int rb = 0; rb < 4; ++rb) {
            int row = rb * 8 + rsub;           // 0..31
            unsigned short* base = &lds[row * XS + lane32 * 4];
            ushort4 p;
            p.x = f2bf(v0[rb].x); p.y = f2bf(v0[rb].y);
            p.z = f2bf(v0[rb].z); p.w = f2bf(v0[rb].w);
            *(ushort4*)(base) = p;
            p.x = f2bf(v1[rb].x); p.y = f2bf(v1[rb].y);
            p.z = f2bf(v1[rb].z); p.w = f2bf(v1[rb].w);
            *(ushort4*)(base + 128) = p;
            p.x = f2bf(v2[rb].x); p.y = f2bf(v2[rb].y);
            p.z = f2bf(v2[rb].z); p.w = f2bf(v2[rb].w);
            *(ushort4*)(base + 256) = p;
        }
    }
    __syncthreads();

    const int w = t >> 6;                 // wave id 0..3 -> column block
    const int lane = t & 63;
    const int lrow = lane & 31;           // m within tile / n within col block
    const int khalf = (lane >> 5) * 8;    // k-half select
    const int n = w * 32 + lrow;
    const int rbump = (lane >> 5) * 4;

    // ---- GEMM1: H = relu(X_cat @ W1 + b1), K = 384 ----
    f32x16 acc;
    #pragma unroll
    for (int i = 0; i < 16; ++i) acc[i] = 0.f;

    #pragma unroll 8
    for (int kt = 0; kt < 24; ++kt) {
        short8 a = *(const short8*)&lds[lrow * XS + kt * 16 + khalf];
        short8 b = *(const short8*)(W1p + ((kt * 4 + w) * 64 + lane) * 8);
        acc = __builtin_amdgcn_mfma_f32_32x32x16_bf16(a, b, acc, 0, 0, 0);
    }
    __syncthreads();   // everyone done reading X_cat before H overwrites it

    {
        float b1v = b1[n];
        #pragma unroll
        for (int r = 0; r < 16; ++r) {
            int rr = (r & 3) + 8 * (r >> 2) + rbump;   // C-layout row within tile
            Hs[rr * HS + n] = f2bf(fmaxf(acc[r] + b1v, 0.f));
        }
    }
    __syncthreads();

    // ---- GEMM2: OUT = H @ W2 + b2, K = 128 ----
    f32x16 c;
    #pragma unroll
    for (int i = 0; i < 16; ++i) c[i] = 0.f;

    #pragma unroll
    for (int kt = 0; kt < 8; ++kt) {
        short8 a = *(const short8*)&Hs[lrow * HS + kt * 16 + khalf];
        short8 b = *(const short8*)(W2p + ((kt * 4 + w) * 64 + lane) * 8);
        c = __builtin_amdgcn_mfma_f32_32x32x16_bf16(a, b, c, 0, 0, 0);
    }

    {
        float b2v = b2[n];
        #pragma unroll
        for (int r = 0; r < 16; ++r) {
            int rr = (r & 3) + 8 * (r >> 2) + rbump;
            int rg = r0 + rr;
            if (rg < E) out[(size_t)rg * D + n] = c[r] + b2v;
        }
    }
}

extern "C" void kernel_launch(void* const* d_in, const int* in_sizes, int n_in,
                              void* d_out, int out_size, void* d_ws, size_t ws_size,
                              hipStream_t stream) {
    const float* x_node = (const float*)d_in[0];
    const float* x_edge = (const float*)d_in[1];
    const int*   eidx   = (const int*)d_in[2];
    const float* W1     = (const float*)d_in[3];
    const float* b1     = (const float*)d_in[4];
    const float* W2     = (const float*)d_in[5];
    const float* b2     = (const float*)d_in[6];
    float* out = (float*)d_out;

    const int E = in_sizes[1] / D;

    unsigned short* W1p = (unsigned short*)d_ws;          // 6144*8 bf16 = 96 KB
    unsigned short* W2p = W1p + 6144 * 8;                 // 2048*8 bf16 = 32 KB

    pack_weights_kernel<<<32, 256, 0, stream>>>(W1, W2, W1p, W2p);

    int nblk = (E + MT - 1) / MT;
    edge_mlp_kernel<<<nblk, 256, 0, stream>>>(x_node, x_edge, eidx, W1p, W2p, b1, b2, out, E);
}